// Round 1
// baseline (6104.240 us; speedup 1.0000x reference)
//
#include <hip/hip_runtime.h>
#include <math.h>

#define S_LEN  4096
#define BATCH  4
#define DMODEL 1024
#define NHEADS 16
#define DHEAD  64
#define WIN    128

// ---------------- fp32 tiled GEMM:  out = A @ W^T + bias ----------------
// A: [M, K] row-major, W: [N, K] row-major (so dot is along contiguous K of both)
// MODE 0: store into qkv workspace with [B, H, S, Dh] layout, z selects W/bias/slab
// MODE 1: store flat [M, N] row-major
#define BM 128
#define BN 128
#define BKK 16

template<int MODE>
__global__ __launch_bounds__(256)
void gemm_nt(const float* __restrict__ A,
             const float* __restrict__ W0, const float* __restrict__ W1, const float* __restrict__ W2,
             const float* __restrict__ B0, const float* __restrict__ B1, const float* __restrict__ B2,
             float* __restrict__ out_base, int M, int K)
{
    const float* W    = (MODE == 0) ? (blockIdx.z == 0 ? W0 : (blockIdx.z == 1 ? W1 : W2)) : W0;
    const float* bias = (MODE == 0) ? (blockIdx.z == 0 ? B0 : (blockIdx.z == 1 ? B1 : B2)) : B0;
    float* out = (MODE == 0) ? out_base + (size_t)blockIdx.z * ((size_t)M * DMODEL) : out_base;

    __shared__ float As[BKK][BM + 4];
    __shared__ float Bs[BKK][BN + 4];

    const int tid  = threadIdx.x;
    const int i0   = blockIdx.y * BM;
    const int n0   = blockIdx.x * BN;
    const int srow = tid >> 1;          // 0..127
    const int scol = (tid & 1) * 8;     // 0 or 8
    const int ty   = tid >> 4;          // 0..15
    const int tx   = tid & 15;          // 0..15

    float acc[8][8];
    #pragma unroll
    for (int r = 0; r < 8; ++r)
        #pragma unroll
        for (int c = 0; c < 8; ++c) acc[r][c] = 0.f;

    const float* Arow = A + (size_t)(i0 + srow) * K + scol;
    const float* Wrow = W + (size_t)(n0 + srow) * K + scol;

    for (int k0 = 0; k0 < K; k0 += BKK) {
        float4 a0 = *(const float4*)(Arow + k0);
        float4 a1 = *(const float4*)(Arow + k0 + 4);
        float4 b0 = *(const float4*)(Wrow + k0);
        float4 b1 = *(const float4*)(Wrow + k0 + 4);
        __syncthreads();
        As[scol + 0][srow] = a0.x; As[scol + 1][srow] = a0.y;
        As[scol + 2][srow] = a0.z; As[scol + 3][srow] = a0.w;
        As[scol + 4][srow] = a1.x; As[scol + 5][srow] = a1.y;
        As[scol + 6][srow] = a1.z; As[scol + 7][srow] = a1.w;
        Bs[scol + 0][srow] = b0.x; Bs[scol + 1][srow] = b0.y;
        Bs[scol + 2][srow] = b0.z; Bs[scol + 3][srow] = b0.w;
        Bs[scol + 4][srow] = b1.x; Bs[scol + 5][srow] = b1.y;
        Bs[scol + 6][srow] = b1.z; Bs[scol + 7][srow] = b1.w;
        __syncthreads();
        #pragma unroll
        for (int kk = 0; kk < BKK; ++kk) {
            float4 fa0 = *(const float4*)&As[kk][ty * 8];
            float4 fa1 = *(const float4*)&As[kk][ty * 8 + 4];
            float4 fb0 = *(const float4*)&Bs[kk][tx * 8];
            float4 fb1 = *(const float4*)&Bs[kk][tx * 8 + 4];
            const float av[8] = {fa0.x, fa0.y, fa0.z, fa0.w, fa1.x, fa1.y, fa1.z, fa1.w};
            const float bv[8] = {fb0.x, fb0.y, fb0.z, fb0.w, fb1.x, fb1.y, fb1.z, fb1.w};
            #pragma unroll
            for (int r = 0; r < 8; ++r)
                #pragma unroll
                for (int c = 0; c < 8; ++c)
                    acc[r][c] = fmaf(av[r], bv[c], acc[r][c]);
        }
    }

    // epilogue
    #pragma unroll
    for (int r = 0; r < 8; ++r) {
        const int row = i0 + ty * 8 + r;        // global row = b*S + sp
        #pragma unroll
        for (int c = 0; c < 8; c += 4) {
            const int m = n0 + tx * 8 + c;      // global col = h*64 + dh
            const float4 bb = *(const float4*)&bias[m];
            float4 val;
            val.x = acc[r][c + 0] + bb.x;
            val.y = acc[r][c + 1] + bb.y;
            val.z = acc[r][c + 2] + bb.z;
            val.w = acc[r][c + 3] + bb.w;
            if (MODE == 0) {
                const int b  = row >> 12;       // / S_LEN
                const int sp = row & (S_LEN - 1);
                const int h  = m >> 6;
                const int dh = m & 63;
                *(float4*)&out[((((size_t)(b * NHEADS + h)) * S_LEN + sp) << 6) + dh] = val;
            } else {
                *(float4*)&out[(size_t)row * DMODEL + m] = val;
            }
        }
    }
}

// ---------------- windowed attention (exact scan semantics) ----------------
// q,k,v: [B, H, S, Dh]; o out: [B, S, H, Dh] (row-major [B*S, D] for final GEMM)
// One wave per query; lane = dh. Ascending-j loop with running (prefix) max,
// NO rescale of accumulators -> bit-faithful to the reference scan.
__global__ __launch_bounds__(256)
void attn_kernel(const float* __restrict__ q, const float* __restrict__ k,
                 const float* __restrict__ v, float* __restrict__ o)
{
    const int lane = threadIdx.x & 63;
    const int wid  = threadIdx.x >> 6;
    const int i    = blockIdx.x * 4 + wid;     // query position
    const int h    = blockIdx.y;
    const int b    = blockIdx.z;
    const size_t bh = (size_t)(b * NHEADS + h);

    const float* kb = k + bh * S_LEN * DHEAD;
    const float* vb = v + bh * S_LEN * DHEAD;
    const float  ql = q[(bh * S_LEN + i) * DHEAD + lane];

    const int jlo = max(0, i - WIN);
    const int jhi = min(S_LEN - 1, i + WIN);

    float m = -INFINITY;
    float oacc = 0.f;
    float ts = 0.f;

    #pragma unroll 2
    for (int j = jlo; j <= jhi; ++j) {
        const float kl = kb[(size_t)j * DHEAD + lane];
        const float vl = vb[(size_t)j * DHEAD + lane];
        float prod = ql * kl;
        #pragma unroll
        for (int d = 1; d < 64; d <<= 1)
            prod += __shfl_xor(prod, d, 64);
        const float s = prod * 0.125f;          // 1/sqrt(64)
        m = fmaxf(m, s);
        const float p = __expf(s - m);
        oacc = fmaf(p, vl, oacc);
        ts += p;
    }

    // out layout [B, S, H, Dh] == row-major [B*S, 1024]
    o[((size_t)(b * S_LEN + i) * NHEADS + h) * DHEAD + lane] = oacc / ts;
}

extern "C" void kernel_launch(void* const* d_in, const int* in_sizes, int n_in,
                              void* d_out, int out_size, void* d_ws, size_t ws_size,
                              hipStream_t stream) {
    const float* x  = (const float*)d_in[0];
    const float* wq = (const float*)d_in[1];
    const float* bq = (const float*)d_in[2];
    const float* wk = (const float*)d_in[3];
    const float* bk = (const float*)d_in[4];
    const float* wv = (const float*)d_in[5];
    const float* bv = (const float*)d_in[6];
    const float* wo = (const float*)d_in[7];
    const float* bo = (const float*)d_in[8];

    float* ws = (float*)d_ws;
    const size_t BUF = (size_t)BATCH * S_LEN * DMODEL;   // 16,777,216 floats
    float* qb = ws;
    float* kb = ws + BUF;
    float* vb = ws + 2 * BUF;
    float* ob = ws + 3 * BUF;                            // needs 256 MB total

    const int M = BATCH * S_LEN;                         // 16384

    // 1) Q/K/V projections (one launch; z selects weight, stores [B,H,S,Dh])
    dim3 gproj(DMODEL / BN, M / BM, 3);
    gemm_nt<0><<<gproj, 256, 0, stream>>>(x, wq, wk, wv, bq, bk, bv, ws, M, DMODEL);

    // 2) windowed attention -> ob in [B,S,H,Dh] (= [M, D] row-major)
    dim3 gattn(S_LEN / 4, NHEADS, BATCH);
    attn_kernel<<<gattn, 256, 0, stream>>>(qb, kb, vb, ob);

    // 3) output projection
    dim3 gout(DMODEL / BN, M / BM, 1);
    gemm_nt<1><<<gout, 256, 0, stream>>>(ob, wo, nullptr, nullptr, bo, nullptr, nullptr,
                                         (float*)d_out, M, DMODEL);
}

// Round 2
// 1987.889 us; speedup vs baseline: 3.0707x; 3.0707x over previous
//
#include <hip/hip_runtime.h>
#include <math.h>

#define S_LEN  4096
#define BATCH  4
#define DMODEL 1024
#define NHEADS 16
#define DHEAD  64
#define WIN    128

// ---------------- fp32 tiled GEMM:  out = A @ W^T + bias ----------------
#define BM 128
#define BN 128
#define BKK 16

template<int MODE>
__global__ __launch_bounds__(256)
void gemm_nt(const float* __restrict__ A,
             const float* __restrict__ W0, const float* __restrict__ W1, const float* __restrict__ W2,
             const float* __restrict__ B0, const float* __restrict__ B1, const float* __restrict__ B2,
             float* __restrict__ out_base, int M, int K)
{
    const float* W    = (MODE == 0) ? (blockIdx.z == 0 ? W0 : (blockIdx.z == 1 ? W1 : W2)) : W0;
    const float* bias = (MODE == 0) ? (blockIdx.z == 0 ? B0 : (blockIdx.z == 1 ? B1 : B2)) : B0;
    float* out = (MODE == 0) ? out_base + (size_t)blockIdx.z * ((size_t)M * DMODEL) : out_base;

    __shared__ float As[BKK][BM + 4];
    __shared__ float Bs[BKK][BN + 4];

    const int tid  = threadIdx.x;
    const int i0   = blockIdx.y * BM;
    const int n0   = blockIdx.x * BN;
    const int srow = tid >> 1;
    const int scol = (tid & 1) * 8;
    const int ty   = tid >> 4;
    const int tx   = tid & 15;

    float acc[8][8];
    #pragma unroll
    for (int r = 0; r < 8; ++r)
        #pragma unroll
        for (int c = 0; c < 8; ++c) acc[r][c] = 0.f;

    const float* Arow = A + (size_t)(i0 + srow) * K + scol;
    const float* Wrow = W + (size_t)(n0 + srow) * K + scol;

    for (int k0 = 0; k0 < K; k0 += BKK) {
        float4 a0 = *(const float4*)(Arow + k0);
        float4 a1 = *(const float4*)(Arow + k0 + 4);
        float4 b0 = *(const float4*)(Wrow + k0);
        float4 b1 = *(const float4*)(Wrow + k0 + 4);
        __syncthreads();
        As[scol + 0][srow] = a0.x; As[scol + 1][srow] = a0.y;
        As[scol + 2][srow] = a0.z; As[scol + 3][srow] = a0.w;
        As[scol + 4][srow] = a1.x; As[scol + 5][srow] = a1.y;
        As[scol + 6][srow] = a1.z; As[scol + 7][srow] = a1.w;
        Bs[scol + 0][srow] = b0.x; Bs[scol + 1][srow] = b0.y;
        Bs[scol + 2][srow] = b0.z; Bs[scol + 3][srow] = b0.w;
        Bs[scol + 4][srow] = b1.x; Bs[scol + 5][srow] = b1.y;
        Bs[scol + 6][srow] = b1.z; Bs[scol + 7][srow] = b1.w;
        __syncthreads();
        #pragma unroll
        for (int kk = 0; kk < BKK; ++kk) {
            float4 fa0 = *(const float4*)&As[kk][ty * 8];
            float4 fa1 = *(const float4*)&As[kk][ty * 8 + 4];
            float4 fb0 = *(const float4*)&Bs[kk][tx * 8];
            float4 fb1 = *(const float4*)&Bs[kk][tx * 8 + 4];
            const float av[8] = {fa0.x, fa0.y, fa0.z, fa0.w, fa1.x, fa1.y, fa1.z, fa1.w};
            const float bv[8] = {fb0.x, fb0.y, fb0.z, fb0.w, fb1.x, fb1.y, fb1.z, fb1.w};
            #pragma unroll
            for (int r = 0; r < 8; ++r)
                #pragma unroll
                for (int c = 0; c < 8; ++c)
                    acc[r][c] = fmaf(av[r], bv[c], acc[r][c]);
        }
    }

    #pragma unroll
    for (int r = 0; r < 8; ++r) {
        const int row = i0 + ty * 8 + r;
        #pragma unroll
        for (int c = 0; c < 8; c += 4) {
            const int m = n0 + tx * 8 + c;
            const float4 bb = *(const float4*)&bias[m];
            float4 val;
            val.x = acc[r][c + 0] + bb.x;
            val.y = acc[r][c + 1] + bb.y;
            val.z = acc[r][c + 2] + bb.z;
            val.w = acc[r][c + 3] + bb.w;
            if (MODE == 0) {
                const int b  = row >> 12;
                const int sp = row & (S_LEN - 1);
                const int h  = m >> 6;
                const int dh = m & 63;
                *(float4*)&out[((((size_t)(b * NHEADS + h)) * S_LEN + sp) << 6) + dh] = val;
            } else {
                *(float4*)&out[(size_t)row * DMODEL + m] = val;
            }
        }
    }
}

// ---------------- fused windowed attention, tiled, exact prefix-max scan ----
// q,k,v: [B,H,S,Dh] fp32. o: [B,S,H,Dh] fp32 (= [B*S, D] row-major).
// Per workgroup: 64-query tile of one (b,h). 5 chunks of 64 keys covering
// the [i-128, i+128] band. Per chunk: S=Q*Kc^T (tile GEMM), segmented
// prefix-max scan (exact reference semantics), O += P*Vc (tile GEMM).
#define TQ  64
#define CK  64
#define LDP 68   // padded LDS row stride (floats)

__global__ __launch_bounds__(256)
void attn_fused(const float* __restrict__ qg_, const float* __restrict__ kg_,
                const float* __restrict__ vg_, float* __restrict__ o)
{
    __shared__ float Qs[DHEAD * LDP];  // Q^T: [d][q], col swizzled by (d&12)
    __shared__ float KV[CK * LDP];     // K^T [d][t] swizzled, reused as V [t][d] plain
    __shared__ float SP[TQ * LDP];     // S [q][t] swizzled by ((q>>1)&12); reused as P^T [t][q] plain
    __shared__ float CM[TQ * 4];       // per-(q, seg) chunk max
    __shared__ float TSs[TQ * 4];      // per-(q, seg) partial sums
    __shared__ float Mq[TQ];           // running prefix max carry
    __shared__ float Tq[TQ];           // running denominator

    const int tid   = threadIdx.x;
    const int qbase = blockIdx.x * TQ;
    const size_t bh = (size_t)(blockIdx.z * NHEADS + blockIdx.y);
    const float* qg = qg_ + bh * (size_t)(S_LEN * DHEAD);
    const float* kg = kg_ + bh * (size_t)(S_LEN * DHEAD);
    const float* vg = vg_ + bh * (size_t)(S_LEN * DHEAD);

    const int tx = tid & 15;     // micro-tile col (t or d)
    const int ty = tid >> 4;     // micro-tile row (q)
    const int sq  = tid & 63;    // scan: query
    const int scc = tid >> 6;    // scan: 16-wide segment 0..3

    // ---- stage Q^T (once) + init carries ----
    {
        const int m  = tid & 15, rr = tid >> 4;
        const int xk = (m & 3) << 2;
        #pragma unroll
        for (int rep = 0; rep < 4; ++rep) {
            const int qq = rep * 16 + rr;
            float4 val = *(const float4*)(qg + (size_t)(qbase + qq) * DHEAD + 4 * m);
            Qs[(4 * m + 0) * LDP + (qq ^ xk)] = val.x;
            Qs[(4 * m + 1) * LDP + (qq ^ xk)] = val.y;
            Qs[(4 * m + 2) * LDP + (qq ^ xk)] = val.z;
            Qs[(4 * m + 3) * LDP + (qq ^ xk)] = val.w;
        }
    }
    if (tid < TQ) { Mq[tid] = -INFINITY; Tq[tid] = 0.f; }

    float Oacc[4][4] = {{0.f}};
    const int j0 = qbase - WIN;

    for (int c = 0; c < 5; ++c) {
        const int jlo = j0 + c * CK;
        if (jlo + CK - 1 < 0 || jlo >= S_LEN) continue;  // uniform skip

        __syncthreads();  // b0: prev PV done / init visible

        // ---- stage K^T chunk (swizzled) ----
        {
            const int m  = tid & 15, rr = tid >> 4;
            const int xk = (m & 3) << 2;
            #pragma unroll
            for (int rep = 0; rep < 4; ++rep) {
                const int t = rep * 16 + rr;
                int j = jlo + t;
                j = j < 0 ? 0 : (j > S_LEN - 1 ? S_LEN - 1 : j);
                float4 val = *(const float4*)(kg + (size_t)j * DHEAD + 4 * m);
                KV[(4 * m + 0) * LDP + (t ^ xk)] = val.x;
                KV[(4 * m + 1) * LDP + (t ^ xk)] = val.y;
                KV[(4 * m + 2) * LDP + (t ^ xk)] = val.z;
                KV[(4 * m + 3) * LDP + (t ^ xk)] = val.w;
            }
        }
        __syncthreads();  // b1

        // ---- GEMM1: S[q][t] = (Q . K) * 1/8 ----
        {
            float acc[4][4] = {{0.f}};
            for (int db = 0; db < DHEAD; db += 16) {
                #pragma unroll
                for (int dd = 0; dd < 16; ++dd) {
                    const int d  = db + dd;
                    const int xd = dd & 12;  // == d&12 since db%16==0
                    float4 a  = *(const float4*)&Qs[d * LDP + ((4 * ty) ^ xd)];
                    float4 b4 = *(const float4*)&KV[d * LDP + ((4 * tx) ^ xd)];
                    acc[0][0] = fmaf(a.x, b4.x, acc[0][0]); acc[0][1] = fmaf(a.x, b4.y, acc[0][1]);
                    acc[0][2] = fmaf(a.x, b4.z, acc[0][2]); acc[0][3] = fmaf(a.x, b4.w, acc[0][3]);
                    acc[1][0] = fmaf(a.y, b4.x, acc[1][0]); acc[1][1] = fmaf(a.y, b4.y, acc[1][1]);
                    acc[1][2] = fmaf(a.y, b4.z, acc[1][2]); acc[1][3] = fmaf(a.y, b4.w, acc[1][3]);
                    acc[2][0] = fmaf(a.z, b4.x, acc[2][0]); acc[2][1] = fmaf(a.z, b4.y, acc[2][1]);
                    acc[2][2] = fmaf(a.z, b4.z, acc[2][2]); acc[2][3] = fmaf(a.z, b4.w, acc[2][3]);
                    acc[3][0] = fmaf(a.w, b4.x, acc[3][0]); acc[3][1] = fmaf(a.w, b4.y, acc[3][1]);
                    acc[3][2] = fmaf(a.w, b4.z, acc[3][2]); acc[3][3] = fmaf(a.w, b4.w, acc[3][3]);
                }
            }
            #pragma unroll
            for (int r = 0; r < 4; ++r) {
                const int qq = 4 * ty + r;
                const int xq = (qq >> 1) & 12;
                float4 val;
                val.x = acc[r][0] * 0.125f; val.y = acc[r][1] * 0.125f;
                val.z = acc[r][2] * 0.125f; val.w = acc[r][3] * 0.125f;
                *(float4*)&SP[qq * LDP + ((4 * tx) ^ xq)] = val;
            }
        }
        __syncthreads();  // b2

        // ---- scan A: per-(q, 16-seg) local prefix max ----
        float sv[16], run[16];
        {
            const int xq = (sq >> 1) & 12;
            float m_run = -INFINITY;
            #pragma unroll
            for (int i = 0; i < 16; ++i) {
                const int t = 16 * scc + i;
                float s = SP[sq * LDP + (t ^ xq)];
                const int j   = jlo + t;
                const int rel = j - (qbase + sq) + WIN;
                const bool valid = (j >= 0) && (j < S_LEN) && (rel >= 0) && (rel <= 2 * WIN);
                s = valid ? s : -INFINITY;
                sv[i]  = s;
                m_run  = fmaxf(m_run, s);
                run[i] = m_run;
            }
            CM[sq * 4 + scc] = m_run;
        }
        __syncthreads();  // b3

        // ---- scan B: combine, exponentiate, write P^T ----
        {
            float pre = Mq[sq];
            #pragma unroll
            for (int kk = 0; kk < 4; ++kk)
                if (kk < scc) pre = fmaxf(pre, CM[sq * 4 + kk]);
            float tl = 0.f;
            #pragma unroll
            for (int i = 0; i < 16; ++i) {
                const int t = 16 * scc + i;
                const float w = fmaxf(pre, run[i]);
                const float p = (sv[i] != -INFINITY) ? __expf(sv[i] - w) : 0.f;
                tl += p;
                SP[t * LDP + sq] = p;  // P^T, plain layout
            }
            TSs[sq * 4 + scc] = tl;
        }
        __syncthreads();  // b4

        // ---- stage V chunk (plain [t][d]) + carry update ----
        {
            const int t = tid >> 2, dq = tid & 3;
            int j = jlo + t;
            j = j < 0 ? 0 : (j > S_LEN - 1 ? S_LEN - 1 : j);
            #pragma unroll
            for (int rep = 0; rep < 4; ++rep) {
                const int d4 = rep * 16 + dq * 4;
                *(float4*)&KV[t * LDP + d4] = *(const float4*)(vg + (size_t)j * DHEAD + d4);
            }
        }
        if (tid < TQ) {
            const float mm = fmaxf(fmaxf(CM[tid * 4 + 0], CM[tid * 4 + 1]),
                                   fmaxf(CM[tid * 4 + 2], CM[tid * 4 + 3]));
            Mq[tid] = fmaxf(Mq[tid], mm);
            Tq[tid] += TSs[tid * 4 + 0] + TSs[tid * 4 + 1] + TSs[tid * 4 + 2] + TSs[tid * 4 + 3];
        }
        __syncthreads();  // b5

        // ---- PV: O += P^T' * V ----
        for (int tb = 0; tb < CK; tb += 16) {
            #pragma unroll
            for (int tt = 0; tt < 16; ++tt) {
                const int t = tb + tt;
                float4 a  = *(const float4*)&SP[t * LDP + 4 * ty];
                float4 b4 = *(const float4*)&KV[t * LDP + 4 * tx];
                Oacc[0][0] = fmaf(a.x, b4.x, Oacc[0][0]); Oacc[0][1] = fmaf(a.x, b4.y, Oacc[0][1]);
                Oacc[0][2] = fmaf(a.x, b4.z, Oacc[0][2]); Oacc[0][3] = fmaf(a.x, b4.w, Oacc[0][3]);
                Oacc[1][0] = fmaf(a.y, b4.x, Oacc[1][0]); Oacc[1][1] = fmaf(a.y, b4.y, Oacc[1][1]);
                Oacc[1][2] = fmaf(a.y, b4.z, Oacc[1][2]); Oacc[1][3] = fmaf(a.y, b4.w, Oacc[1][3]);
                Oacc[2][0] = fmaf(a.z, b4.x, Oacc[2][0]); Oacc[2][1] = fmaf(a.z, b4.y, Oacc[2][1]);
                Oacc[2][2] = fmaf(a.z, b4.z, Oacc[2][2]); Oacc[2][3] = fmaf(a.z, b4.w, Oacc[2][3]);
                Oacc[3][0] = fmaf(a.w, b4.x, Oacc[3][0]); Oacc[3][1] = fmaf(a.w, b4.y, Oacc[3][1]);
                Oacc[3][2] = fmaf(a.w, b4.z, Oacc[3][2]); Oacc[3][3] = fmaf(a.w, b4.w, Oacc[3][3]);
            }
        }
    }

    // ---- epilogue: O / Tq -> [B,S,H,Dh] ----
    #pragma unroll
    for (int r = 0; r < 4; ++r) {
        const int qq  = 4 * ty + r;
        const float inv = 1.0f / Tq[qq];
        float4 val;
        val.x = Oacc[r][0] * inv; val.y = Oacc[r][1] * inv;
        val.z = Oacc[r][2] * inv; val.w = Oacc[r][3] * inv;
        o[(((size_t)blockIdx.z * S_LEN + qbase + qq) * NHEADS + blockIdx.y) * DHEAD + 4 * tx] = val.x,
        // use a proper float4 store:
        *(float4*)&o[(((size_t)blockIdx.z * S_LEN + qbase + qq) * NHEADS + blockIdx.y) * DHEAD + 4 * tx] = val;
    }
}

extern "C" void kernel_launch(void* const* d_in, const int* in_sizes, int n_in,
                              void* d_out, int out_size, void* d_ws, size_t ws_size,
                              hipStream_t stream) {
    const float* x  = (const float*)d_in[0];
    const float* wq = (const float*)d_in[1];
    const float* bq = (const float*)d_in[2];
    const float* wk = (const float*)d_in[3];
    const float* bk = (const float*)d_in[4];
    const float* wv = (const float*)d_in[5];
    const float* bv = (const float*)d_in[6];
    const float* wo = (const float*)d_in[7];
    const float* bo = (const float*)d_in[8];

    float* ws = (float*)d_ws;
    const size_t BUF = (size_t)BATCH * S_LEN * DMODEL;
    float* qb = ws;
    float* kb = ws + BUF;
    float* vb = ws + 2 * BUF;
    float* ob = ws + 3 * BUF;

    const int M = BATCH * S_LEN;

    dim3 gproj(DMODEL / BN, M / BM, 3);
    gemm_nt<0><<<gproj, 256, 0, stream>>>(x, wq, wk, wv, bq, bk, bv, ws, M, DMODEL);

    dim3 gattn(S_LEN / TQ, NHEADS, BATCH);
    attn_fused<<<gattn, 256, 0, stream>>>(qb, kb, vb, ob);

    dim3 gout(DMODEL / BN, M / BM, 1);
    gemm_nt<1><<<gout, 256, 0, stream>>>(ob, wo, nullptr, nullptr, bo, nullptr, nullptr,
                                         (float*)d_out, M, DMODEL);
}

// Round 3
// 626.225 us; speedup vs baseline: 9.7477x; 3.1744x over previous
//
#include <hip/hip_runtime.h>
#include <math.h>

#define S_LEN  4096
#define BATCH  4
#define DMODEL 1024
#define NHEADS 16
#define DHEAD  64
#define WIN    128

typedef _Float16 half8   __attribute__((ext_vector_type(8)));
typedef _Float16 half4_t __attribute__((ext_vector_type(4)));
typedef float    floatx4 __attribute__((ext_vector_type(4)));

__device__ __forceinline__ void gload16(const void* g, void* l) {
    __builtin_amdgcn_global_load_lds(
        (const __attribute__((address_space(1))) void*)g,
        (__attribute__((address_space(3))) void*)l, 16, 0, 0);
}

// ---------------- fp32 -> fp16 conversion (memory-bound) ----------------
__global__ __launch_bounds__(256)
void cvt_f32_f16(const float4* __restrict__ in, half4_t* __restrict__ out, int n4) {
    for (int i = blockIdx.x * blockDim.x + threadIdx.x; i < n4;
         i += gridDim.x * blockDim.x) {
        const float4 a = in[i];
        half4_t h;
        h[0] = (_Float16)a.x; h[1] = (_Float16)a.y;
        h[2] = (_Float16)a.z; h[3] = (_Float16)a.w;
        out[i] = h;
    }
}

// ---------------- f16 MFMA GEMM:  out = A @ W^T + bias (m97 structure) ----
// A: [M,K] f16 row-major. W: [N,K] f16 row-major. out fp32.
// 128x128 tile, BK=32, 4 waves (2x2), mfma_f32_16x16x32_f16, gload_lds w=16.
// MODE 0: scatter to [B,H,S,Dh], z selects W/bias/slab.  MODE 1: flat [M,N].
template<int MODE>
__global__ __launch_bounds__(256)
void gemm_f16(const _Float16* __restrict__ A,
              const _Float16* __restrict__ W0, const _Float16* __restrict__ W1,
              const _Float16* __restrict__ W2,
              const float* __restrict__ B0, const float* __restrict__ B1,
              const float* __restrict__ B2,
              float* __restrict__ out_base)
{
    const int K = DMODEL;
    const _Float16* W    = (MODE == 0) ? (blockIdx.z == 0 ? W0 : (blockIdx.z == 1 ? W1 : W2)) : W0;
    const float*    bias = (MODE == 0) ? (blockIdx.z == 0 ? B0 : (blockIdx.z == 1 ? B1 : B2)) : B0;
    float* out = (MODE == 0) ? out_base + (size_t)blockIdx.z * ((size_t)16384 * DMODEL) : out_base;

    __shared__ _Float16 As[128 * 32];
    __shared__ _Float16 Bs[128 * 32];

    const int tid  = threadIdx.x;
    const int lane = tid & 63;
    const int wid  = tid >> 6;
    const int wr   = wid >> 1, wc = wid & 1;
    const int i0   = blockIdx.y * 128;
    const int n0   = blockIdx.x * 128;

    // staging: thread t covers bytes t*16 of each 4KB half-tile (linear LDS)
    const int srow = tid >> 2;           // 0..63
    const int scol = (tid & 3) * 8;      // k-offset in f16
    const _Float16* gA0 = A + (size_t)(i0 + srow) * K + scol;
    const _Float16* gA1 = A + (size_t)(i0 + 64 + srow) * K + scol;
    const _Float16* gB0 = W + (size_t)(n0 + srow) * K + scol;
    const _Float16* gB1 = W + (size_t)(n0 + 64 + srow) * K + scol;
    _Float16* lA0 = As + tid * 8;
    _Float16* lA1 = As + 2048 + tid * 8;
    _Float16* lB0 = Bs + tid * 8;
    _Float16* lB1 = Bs + 2048 + tid * 8;

    floatx4 acc[4][4];
    #pragma unroll
    for (int mi = 0; mi < 4; ++mi)
        #pragma unroll
        for (int ni = 0; ni < 4; ++ni) acc[mi][ni] = (floatx4)0.f;

    // fragment read offsets (f16 units): row*(BK=32) + k
    const int frow = lane & 15;
    const int fk   = (lane >> 4) * 8;
    const int aoff = (wr * 64 + frow) * 32 + fk;   // + mi*16*32
    const int boff = (wc * 64 + frow) * 32 + fk;   // + ni*16*32

    for (int k0 = 0; k0 < K; k0 += 32) {
        gload16(gA0 + k0, lA0);
        gload16(gA1 + k0, lA1);
        gload16(gB0 + k0, lB0);
        gload16(gB1 + k0, lB1);
        __syncthreads();

        half8 a[4], b[4];
        #pragma unroll
        for (int mi = 0; mi < 4; ++mi) a[mi] = *(const half8*)&As[aoff + mi * 512];
        #pragma unroll
        for (int ni = 0; ni < 4; ++ni) b[ni] = *(const half8*)&Bs[boff + ni * 512];
        #pragma unroll
        for (int mi = 0; mi < 4; ++mi)
            #pragma unroll
            for (int ni = 0; ni < 4; ++ni)
                acc[mi][ni] = __builtin_amdgcn_mfma_f32_16x16x32_f16(
                    a[mi], b[ni], acc[mi][ni], 0, 0, 0);
        __syncthreads();
    }

    // epilogue: C/D layout col=lane&15, row=(lane>>4)*4+reg
    const int r0 = (lane >> 4) * 4;
    const int cn = lane & 15;
    #pragma unroll
    for (int ni = 0; ni < 4; ++ni) {
        const int gc = n0 + wc * 64 + ni * 16 + cn;
        const float bv = bias[gc];
        #pragma unroll
        for (int mi = 0; mi < 4; ++mi) {
            const int gr = i0 + wr * 64 + mi * 16 + r0;
            const floatx4 v = acc[mi][ni];
            #pragma unroll
            for (int r = 0; r < 4; ++r) {
                const float val = v[r] + bv;
                if (MODE == 0) {
                    const int row = gr + r;
                    const int b  = row >> 12;
                    const int sp = row & (S_LEN - 1);
                    const int h  = gc >> 6;
                    const int dh = gc & 63;
                    out[((((size_t)(b * NHEADS + h)) * S_LEN + sp) << 6) + dh] = val;
                } else {
                    out[(size_t)(gr + r) * DMODEL + gc] = val;
                }
            }
        }
    }
}

// ---------------- fused windowed attention, tiled, exact prefix-max scan ----
// q,k,v: [B,H,S,Dh] fp32. o: [B,S,H,Dh] f16 (= [B*S, D] row-major).
#define TQ  64
#define CK  64
#define LDP 68

__global__ __launch_bounds__(256)
void attn_fused(const float* __restrict__ qg_, const float* __restrict__ kg_,
                const float* __restrict__ vg_, _Float16* __restrict__ o)
{
    __shared__ float Qs[DHEAD * LDP];
    __shared__ float KV[CK * LDP];
    __shared__ float SP[TQ * LDP];
    __shared__ float CM[TQ * 4];
    __shared__ float TSs[TQ * 4];
    __shared__ float Mq[TQ];
    __shared__ float Tq[TQ];

    const int tid   = threadIdx.x;
    const int qbase = blockIdx.x * TQ;
    const size_t bh = (size_t)(blockIdx.z * NHEADS + blockIdx.y);
    const float* qg = qg_ + bh * (size_t)(S_LEN * DHEAD);
    const float* kg = kg_ + bh * (size_t)(S_LEN * DHEAD);
    const float* vg = vg_ + bh * (size_t)(S_LEN * DHEAD);

    const int tx  = tid & 15;
    const int ty  = tid >> 4;
    const int sq  = tid & 63;
    const int scc = tid >> 6;

    {
        const int m  = tid & 15, rr = tid >> 4;
        const int xk = (m & 3) << 2;
        #pragma unroll
        for (int rep = 0; rep < 4; ++rep) {
            const int qq = rep * 16 + rr;
            float4 val = *(const float4*)(qg + (size_t)(qbase + qq) * DHEAD + 4 * m);
            Qs[(4 * m + 0) * LDP + (qq ^ xk)] = val.x;
            Qs[(4 * m + 1) * LDP + (qq ^ xk)] = val.y;
            Qs[(4 * m + 2) * LDP + (qq ^ xk)] = val.z;
            Qs[(4 * m + 3) * LDP + (qq ^ xk)] = val.w;
        }
    }
    if (tid < TQ) { Mq[tid] = -INFINITY; Tq[tid] = 0.f; }

    float Oacc[4][4] = {{0.f}};
    const int j0 = qbase - WIN;

    for (int c = 0; c < 5; ++c) {
        const int jlo = j0 + c * CK;
        if (jlo + CK - 1 < 0 || jlo >= S_LEN) continue;

        __syncthreads();

        {
            const int m  = tid & 15, rr = tid >> 4;
            const int xk = (m & 3) << 2;
            #pragma unroll
            for (int rep = 0; rep < 4; ++rep) {
                const int t = rep * 16 + rr;
                int j = jlo + t;
                j = j < 0 ? 0 : (j > S_LEN - 1 ? S_LEN - 1 : j);
                float4 val = *(const float4*)(kg + (size_t)j * DHEAD + 4 * m);
                KV[(4 * m + 0) * LDP + (t ^ xk)] = val.x;
                KV[(4 * m + 1) * LDP + (t ^ xk)] = val.y;
                KV[(4 * m + 2) * LDP + (t ^ xk)] = val.z;
                KV[(4 * m + 3) * LDP + (t ^ xk)] = val.w;
            }
        }
        __syncthreads();

        {
            float acc[4][4] = {{0.f}};
            for (int db = 0; db < DHEAD; db += 16) {
                #pragma unroll
                for (int dd = 0; dd < 16; ++dd) {
                    const int d  = db + dd;
                    const int xd = dd & 12;
                    float4 a  = *(const float4*)&Qs[d * LDP + ((4 * ty) ^ xd)];
                    float4 b4 = *(const float4*)&KV[d * LDP + ((4 * tx) ^ xd)];
                    acc[0][0] = fmaf(a.x, b4.x, acc[0][0]); acc[0][1] = fmaf(a.x, b4.y, acc[0][1]);
                    acc[0][2] = fmaf(a.x, b4.z, acc[0][2]); acc[0][3] = fmaf(a.x, b4.w, acc[0][3]);
                    acc[1][0] = fmaf(a.y, b4.x, acc[1][0]); acc[1][1] = fmaf(a.y, b4.y, acc[1][1]);
                    acc[1][2] = fmaf(a.y, b4.z, acc[1][2]); acc[1][3] = fmaf(a.y, b4.w, acc[1][3]);
                    acc[2][0] = fmaf(a.z, b4.x, acc[2][0]); acc[2][1] = fmaf(a.z, b4.y, acc[2][1]);
                    acc[2][2] = fmaf(a.z, b4.z, acc[2][2]); acc[2][3] = fmaf(a.z, b4.w, acc[2][3]);
                    acc[3][0] = fmaf(a.w, b4.x, acc[3][0]); acc[3][1] = fmaf(a.w, b4.y, acc[3][1]);
                    acc[3][2] = fmaf(a.w, b4.z, acc[3][2]); acc[3][3] = fmaf(a.w, b4.w, acc[3][3]);
                }
            }
            #pragma unroll
            for (int r = 0; r < 4; ++r) {
                const int qq = 4 * ty + r;
                const int xq = (qq >> 1) & 12;
                float4 val;
                val.x = acc[r][0] * 0.125f; val.y = acc[r][1] * 0.125f;
                val.z = acc[r][2] * 0.125f; val.w = acc[r][3] * 0.125f;
                *(float4*)&SP[qq * LDP + ((4 * tx) ^ xq)] = val;
            }
        }
        __syncthreads();

        float sv[16], run[16];
        {
            const int xq = (sq >> 1) & 12;
            float m_run = -INFINITY;
            #pragma unroll
            for (int i = 0; i < 16; ++i) {
                const int t = 16 * scc + i;
                float s = SP[sq * LDP + (t ^ xq)];
                const int j   = jlo + t;
                const int rel = j - (qbase + sq) + WIN;
                const bool valid = (j >= 0) && (j < S_LEN) && (rel >= 0) && (rel <= 2 * WIN);
                s = valid ? s : -INFINITY;
                sv[i]  = s;
                m_run  = fmaxf(m_run, s);
                run[i] = m_run;
            }
            CM[sq * 4 + scc] = m_run;
        }
        __syncthreads();

        {
            float pre = Mq[sq];
            #pragma unroll
            for (int kk = 0; kk < 4; ++kk)
                if (kk < scc) pre = fmaxf(pre, CM[sq * 4 + kk]);
            float tl = 0.f;
            #pragma unroll
            for (int i = 0; i < 16; ++i) {
                const int t = 16 * scc + i;
                const float w = fmaxf(pre, run[i]);
                const float p = (sv[i] != -INFINITY) ? __expf(sv[i] - w) : 0.f;
                tl += p;
                SP[t * LDP + sq] = p;
            }
            TSs[sq * 4 + scc] = tl;
        }
        __syncthreads();

        {
            const int t = tid >> 2, dq = tid & 3;
            int j = jlo + t;
            j = j < 0 ? 0 : (j > S_LEN - 1 ? S_LEN - 1 : j);
            #pragma unroll
            for (int rep = 0; rep < 4; ++rep) {
                const int d4 = rep * 16 + dq * 4;
                *(float4*)&KV[t * LDP + d4] = *(const float4*)(vg + (size_t)j * DHEAD + d4);
            }
        }
        if (tid < TQ) {
            const float mm = fmaxf(fmaxf(CM[tid * 4 + 0], CM[tid * 4 + 1]),
                                   fmaxf(CM[tid * 4 + 2], CM[tid * 4 + 3]));
            Mq[tid] = fmaxf(Mq[tid], mm);
            Tq[tid] += TSs[tid * 4 + 0] + TSs[tid * 4 + 1] + TSs[tid * 4 + 2] + TSs[tid * 4 + 3];
        }
        __syncthreads();

        for (int tb = 0; tb < CK; tb += 16) {
            #pragma unroll
            for (int tt = 0; tt < 16; ++tt) {
                const int t = tb + tt;
                float4 a  = *(const float4*)&SP[t * LDP + 4 * ty];
                float4 b4 = *(const float4*)&KV[t * LDP + 4 * tx];
                Oacc[0][0] = fmaf(a.x, b4.x, Oacc[0][0]); Oacc[0][1] = fmaf(a.x, b4.y, Oacc[0][1]);
                Oacc[0][2] = fmaf(a.x, b4.z, Oacc[0][2]); Oacc[0][3] = fmaf(a.x, b4.w, Oacc[0][3]);
                Oacc[1][0] = fmaf(a.y, b4.x, Oacc[1][0]); Oacc[1][1] = fmaf(a.y, b4.y, Oacc[1][1]);
                Oacc[1][2] = fmaf(a.y, b4.z, Oacc[1][2]); Oacc[1][3] = fmaf(a.y, b4.w, Oacc[1][3]);
                Oacc[2][0] = fmaf(a.z, b4.x, Oacc[2][0]); Oacc[2][1] = fmaf(a.z, b4.y, Oacc[2][1]);
                Oacc[2][2] = fmaf(a.z, b4.z, Oacc[2][2]); Oacc[2][3] = fmaf(a.z, b4.w, Oacc[2][3]);
                Oacc[3][0] = fmaf(a.w, b4.x, Oacc[3][0]); Oacc[3][1] = fmaf(a.w, b4.y, Oacc[3][1]);
                Oacc[3][2] = fmaf(a.w, b4.z, Oacc[3][2]); Oacc[3][3] = fmaf(a.w, b4.w, Oacc[3][3]);
            }
        }
    }

    #pragma unroll
    for (int r = 0; r < 4; ++r) {
        const int qq  = 4 * ty + r;
        const float inv = 1.0f / Tq[qq];
        half4_t hv;
        hv[0] = (_Float16)(Oacc[r][0] * inv);
        hv[1] = (_Float16)(Oacc[r][1] * inv);
        hv[2] = (_Float16)(Oacc[r][2] * inv);
        hv[3] = (_Float16)(Oacc[r][3] * inv);
        *(half4_t*)&o[(((size_t)blockIdx.z * S_LEN + qbase + qq) * NHEADS + blockIdx.y) * DHEAD + 4 * tx] = hv;
    }
}

extern "C" void kernel_launch(void* const* d_in, const int* in_sizes, int n_in,
                              void* d_out, int out_size, void* d_ws, size_t ws_size,
                              hipStream_t stream) {
    const float* x  = (const float*)d_in[0];
    const float* wq = (const float*)d_in[1];
    const float* bq = (const float*)d_in[2];
    const float* wk = (const float*)d_in[3];
    const float* bk = (const float*)d_in[4];
    const float* wv = (const float*)d_in[5];
    const float* bv = (const float*)d_in[6];
    const float* wo = (const float*)d_in[7];
    const float* bo = (const float*)d_in[8];

    char* ws = (char*)d_ws;
    const size_t BUF = (size_t)BATCH * S_LEN * DMODEL;          // 16,777,216
    float* qb = (float*)ws;                                     // 3 fp32 slabs
    float* kb = qb + BUF;
    float* vb = kb + BUF;
    _Float16* xh  = (_Float16*)(ws + 3 * BUF * sizeof(float));  // 33.5 MB
    _Float16* oh  = xh;                                         // reuse after proj
    _Float16* wqh = xh + BUF;
    _Float16* wkh = wqh + DMODEL * DMODEL;
    _Float16* wvh = wkh + DMODEL * DMODEL;
    _Float16* woh = wvh + DMODEL * DMODEL;                      // ends at 243 MB

    // 1) fp32 -> f16 conversions
    cvt_f32_f16<<<2048, 256, 0, stream>>>((const float4*)x,  (half4_t*)xh,  (int)(BUF / 4));
    cvt_f32_f16<<<512,  256, 0, stream>>>((const float4*)wq, (half4_t*)wqh, DMODEL * DMODEL / 4);
    cvt_f32_f16<<<512,  256, 0, stream>>>((const float4*)wk, (half4_t*)wkh, DMODEL * DMODEL / 4);
    cvt_f32_f16<<<512,  256, 0, stream>>>((const float4*)wv, (half4_t*)wvh, DMODEL * DMODEL / 4);
    cvt_f32_f16<<<512,  256, 0, stream>>>((const float4*)wo, (half4_t*)woh, DMODEL * DMODEL / 4);

    // 2) Q/K/V projections (f16 MFMA, fp32 out scattered to [B,H,S,Dh])
    dim3 gproj(DMODEL / 128, (BATCH * S_LEN) / 128, 3);
    gemm_f16<0><<<gproj, 256, 0, stream>>>(xh, wqh, wkh, wvh, bq, bk, bv, qb);

    // 3) windowed attention (fp32 math) -> oh f16 [B,S,H,Dh]
    dim3 gattn(S_LEN / TQ, NHEADS, BATCH);
    attn_fused<<<gattn, 256, 0, stream>>>(qb, kb, vb, oh);

    // 4) output projection
    dim3 gout(DMODEL / 128, (BATCH * S_LEN) / 128, 1);
    gemm_f16<1><<<gout, 256, 0, stream>>>(oh, woh, nullptr, nullptr, bo, nullptr, nullptr,
                                          (float*)d_out);
}

// Round 4
// 327.242 us; speedup vs baseline: 18.6536x; 1.9136x over previous
//
#include <hip/hip_runtime.h>
#include <math.h>

#define S_LEN  4096
#define BATCH  4
#define DMODEL 1024
#define NHEADS 16
#define DHEAD  64
#define WIN    128

typedef _Float16 half8   __attribute__((ext_vector_type(8)));
typedef _Float16 half4_t __attribute__((ext_vector_type(4)));
typedef float    floatx4 __attribute__((ext_vector_type(4)));

__device__ __forceinline__ void gload16(const void* g, void* l) {
    __builtin_amdgcn_global_load_lds(
        (const __attribute__((address_space(1))) void*)g,
        (__attribute__((address_space(3))) void*)l, 16, 0, 0);
}

// ---------------- fp32 -> fp16 conversion (memory-bound) ----------------
__global__ __launch_bounds__(256)
void cvt_f32_f16(const float4* __restrict__ in, half4_t* __restrict__ out, int n4) {
    for (int i = blockIdx.x * blockDim.x + threadIdx.x; i < n4;
         i += gridDim.x * blockDim.x) {
        const float4 a = in[i];
        half4_t h;
        h[0] = (_Float16)a.x; h[1] = (_Float16)a.y;
        h[2] = (_Float16)a.z; h[3] = (_Float16)a.w;
        out[i] = h;
    }
}

// ---------------- f16 MFMA GEMM:  out = A @ W^T + bias (m97 structure) ----
// MODE 0: f16 out; z=0,1 -> [B,H,S,Dh]; z=2 -> V^T [B,H,Dh,S]. MODE 1: fp32 flat [M,N].
template<int MODE>
__global__ __launch_bounds__(256)
void gemm_f16(const _Float16* __restrict__ A,
              const _Float16* __restrict__ W0, const _Float16* __restrict__ W1,
              const _Float16* __restrict__ W2,
              const float* __restrict__ B0, const float* __restrict__ B1,
              const float* __restrict__ B2,
              void* __restrict__ out_base)
{
    const int K = DMODEL;
    const _Float16* W    = (MODE == 0) ? (blockIdx.z == 0 ? W0 : (blockIdx.z == 1 ? W1 : W2)) : W0;
    const float*    bias = (MODE == 0) ? (blockIdx.z == 0 ? B0 : (blockIdx.z == 1 ? B1 : B2)) : B0;

    __shared__ _Float16 As[128 * 32];
    __shared__ _Float16 Bs[128 * 32];

    const int tid  = threadIdx.x;
    const int lane = tid & 63;
    const int wid  = tid >> 6;
    const int wr   = wid >> 1, wc = wid & 1;
    const int i0   = blockIdx.y * 128;
    const int n0   = blockIdx.x * 128;

    const int srow = tid >> 2;
    const int scol = (tid & 3) * 8;
    const _Float16* gA0 = A + (size_t)(i0 + srow) * K + scol;
    const _Float16* gA1 = A + (size_t)(i0 + 64 + srow) * K + scol;
    const _Float16* gB0 = W + (size_t)(n0 + srow) * K + scol;
    const _Float16* gB1 = W + (size_t)(n0 + 64 + srow) * K + scol;
    _Float16* lA0 = As + tid * 8;
    _Float16* lA1 = As + 2048 + tid * 8;
    _Float16* lB0 = Bs + tid * 8;
    _Float16* lB1 = Bs + 2048 + tid * 8;

    floatx4 acc[4][4];
    #pragma unroll
    for (int mi = 0; mi < 4; ++mi)
        #pragma unroll
        for (int ni = 0; ni < 4; ++ni) acc[mi][ni] = (floatx4)0.f;

    const int frow = lane & 15;
    const int fk   = (lane >> 4) * 8;
    const int aoff = (wr * 64 + frow) * 32 + fk;
    const int boff = (wc * 64 + frow) * 32 + fk;

    for (int k0 = 0; k0 < K; k0 += 32) {
        gload16(gA0 + k0, lA0);
        gload16(gA1 + k0, lA1);
        gload16(gB0 + k0, lB0);
        gload16(gB1 + k0, lB1);
        __syncthreads();

        half8 a[4], b[4];
        #pragma unroll
        for (int mi = 0; mi < 4; ++mi) a[mi] = *(const half8*)&As[aoff + mi * 512];
        #pragma unroll
        for (int ni = 0; ni < 4; ++ni) b[ni] = *(const half8*)&Bs[boff + ni * 512];
        #pragma unroll
        for (int mi = 0; mi < 4; ++mi)
            #pragma unroll
            for (int ni = 0; ni < 4; ++ni)
                acc[mi][ni] = __builtin_amdgcn_mfma_f32_16x16x32_f16(
                    a[mi], b[ni], acc[mi][ni], 0, 0, 0);
        __syncthreads();
    }

    const int r0 = (lane >> 4) * 4;
    const int cn = lane & 15;
    #pragma unroll
    for (int ni = 0; ni < 4; ++ni) {
        const int gc = n0 + wc * 64 + ni * 16 + cn;
        const float bv = bias[gc];
        #pragma unroll
        for (int mi = 0; mi < 4; ++mi) {
            const int gr = i0 + wr * 64 + mi * 16 + r0;
            const floatx4 v = acc[mi][ni];
            if (MODE == 0) {
                _Float16* outh = (_Float16*)out_base
                               + (size_t)blockIdx.z * ((size_t)16384 * DMODEL);
                const int b  = gr >> 12;
                const int sp = gr & (S_LEN - 1);
                const int h  = gc >> 6;
                const int dh = gc & 63;
                if (blockIdx.z < 2) {
                    #pragma unroll
                    for (int r = 0; r < 4; ++r)
                        outh[((((size_t)(b * NHEADS + h)) * S_LEN + sp + r) << 6) + dh] =
                            (_Float16)(v[r] + bv);
                } else {
                    half4_t hv;
                    hv[0] = (_Float16)(v[0] + bv); hv[1] = (_Float16)(v[1] + bv);
                    hv[2] = (_Float16)(v[2] + bv); hv[3] = (_Float16)(v[3] + bv);
                    *(half4_t*)&outh[(((size_t)(b * NHEADS + h)) * DHEAD + dh) * S_LEN + sp] = hv;
                }
            } else {
                float* out = (float*)out_base;
                #pragma unroll
                for (int r = 0; r < 4; ++r)
                    out[(size_t)(gr + r) * DMODEL + gc] = v[r] + bv;
            }
        }
    }
}

// ---------------- MFMA windowed attention, exact prefix-max scan ----------
// qh,kh: [B,H,S,Dh] f16; vth: [B,H,Dh,S] f16; o: [B,S,H,Dh] f16.
// Per wg: 64 queries of one (b,h), 4 waves, 5 chunks of 64 keys.
// All f16 LDS tiles use slot^=(row&7) XOR swizzle (16B slots); sources
// pre-swizzled for linear global_load_lds (rule #21).
__global__ __launch_bounds__(256)
void attn_mfma(const _Float16* __restrict__ qh_, const _Float16* __restrict__ kh_,
               const _Float16* __restrict__ vth_, _Float16* __restrict__ o)
{
    __shared__ __align__(16) _Float16 Qs[64 * 64];
    __shared__ __align__(16) _Float16 Ks[64 * 64];
    __shared__ __align__(16) _Float16 Vt[64 * 64];
    __shared__ __align__(16) float    SP[64 * 68];
    __shared__ __align__(16) _Float16 P16[64 * 64];
    __shared__ float CM[64 * 4];
    __shared__ float TSs[64 * 4];
    __shared__ float Mq[64];
    __shared__ float Tq[64];

    const int tid   = threadIdx.x;
    const int lane  = tid & 63;
    const int w     = tid >> 6;         // wave id = q-subtile = scan segment
    const int qbase = blockIdx.x * 64;
    const int head  = blockIdx.y, b = blockIdx.z;
    const size_t bh = (size_t)(b * NHEADS + head);

    const _Float16* qg = qh_  + bh * (size_t)(S_LEN * DHEAD);
    const _Float16* kg = kh_  + bh * (size_t)(S_LEN * DHEAD);
    const _Float16* vg = vth_ + bh * (size_t)(DHEAD * S_LEN);  // rows d, cols s

    const int fr = lane & 15;       // fragment row/col within 16-tile
    const int fh = lane >> 4;       // fragment k-slot 0..3

    // ---- stage Q once (pre-swizzled source) ----
    #pragma unroll
    for (int rep = 0; rep < 2; ++rep) {
        const int c = tid + 256 * rep;
        const int row = c >> 3, sl = c & 7;
        gload16(qg + (size_t)(qbase + row) * 64 + (size_t)((sl ^ (row & 7)) * 8),
                Qs + (size_t)c * 8);
    }
    if (tid < 64) { Mq[tid] = -INFINITY; Tq[tid] = 0.f; }

    floatx4 Oacc[4];
    #pragma unroll
    for (int ni = 0; ni < 4; ++ni) Oacc[ni] = (floatx4)0.f;

    for (int c = 0; c < 5; ++c) {
        const int jlo = qbase - WIN + c * 64;
        if (jlo < 0 || jlo >= S_LEN) continue;   // chunk fully out of range
        const int base_rel = jlo - qbase + WIN;  // rel = base_rel + t - sq

        __syncthreads();  // protect Ks/Vt/P16 from previous chunk's readers

        // ---- stage K chunk + V^T chunk ----
        #pragma unroll
        for (int rep = 0; rep < 2; ++rep) {
            const int cc = tid + 256 * rep;
            const int row = cc >> 3, sl = cc & 7;
            gload16(kg + (size_t)(jlo + row) * 64 + (size_t)((sl ^ (row & 7)) * 8),
                    Ks + (size_t)cc * 8);
            gload16(vg + (size_t)row * S_LEN + jlo + (size_t)((sl ^ (row & 7)) * 8),
                    Vt + (size_t)cc * 8);
        }
        __syncthreads();  // staged data visible

        // ---- QK^T: wave w computes S rows 16w..16w+15 ----
        {
            floatx4 acc[4];
            #pragma unroll
            for (int ni = 0; ni < 4; ++ni) acc[ni] = (floatx4)0.f;
            half8 a[2];
            #pragma unroll
            for (int kc = 0; kc < 2; ++kc) {
                const int row = 16 * w + fr;
                a[kc] = *(const half8*)&Qs[row * 64 + ((fh + 4 * kc) ^ (row & 7)) * 8];
            }
            #pragma unroll
            for (int ni = 0; ni < 4; ++ni)
                #pragma unroll
                for (int kc = 0; kc < 2; ++kc) {
                    const int tr = 16 * ni + fr;
                    half8 bf = *(const half8*)&Ks[tr * 64 + ((fh + 4 * kc) ^ (tr & 7)) * 8];
                    acc[ni] = __builtin_amdgcn_mfma_f32_16x16x32_f16(a[kc], bf, acc[ni], 0, 0, 0);
                }
            #pragma unroll
            for (int ni = 0; ni < 4; ++ni)
                #pragma unroll
                for (int r = 0; r < 4; ++r)
                    SP[(16 * w + 4 * fh + r) * 68 + fr + 16 * ni] = acc[ni][r] * 0.125f;
        }
        __syncthreads();

        // ---- scan A: thread (sq=lane, seg=w) local prefix over 16 keys ----
        const int sq = lane;
        float sv[16], run[16];
        {
            float m_run = -INFINITY;
            #pragma unroll
            for (int u = 0; u < 4; ++u) {
                const float4 s4 = *(const float4*)&SP[sq * 68 + w * 16 + 4 * u];
                const float se[4] = {s4.x, s4.y, s4.z, s4.w};
                #pragma unroll
                for (int e = 0; e < 4; ++e) {
                    const int i = 4 * u + e;
                    const int rel = base_rel + 16 * w + i - sq;
                    const bool valid = (rel >= 0) && (rel <= 2 * WIN);
                    const float s = valid ? se[e] : -INFINITY;
                    sv[i] = s;
                    m_run = fmaxf(m_run, s);
                    run[i] = m_run;
                }
            }
            CM[sq * 4 + w] = m_run;
        }
        __syncthreads();

        // ---- scan B: combine with earlier segments + carry, exp, write P ----
        {
            float pre = Mq[sq];
            if (w > 0) pre = fmaxf(pre, CM[sq * 4 + 0]);
            if (w > 1) pre = fmaxf(pre, CM[sq * 4 + 1]);
            if (w > 2) pre = fmaxf(pre, CM[sq * 4 + 2]);
            float tl = 0.f;
            _Float16 pf[16];
            #pragma unroll
            for (int i = 0; i < 16; ++i) {
                const float wv = fmaxf(pre, run[i]);
                const float p = (sv[i] != -INFINITY) ? __expf(sv[i] - wv) : 0.f;
                tl += p;
                pf[i] = (_Float16)p;
            }
            TSs[sq * 4 + w] = tl;
            #pragma unroll
            for (int u = 0; u < 2; ++u) {
                half8 h8;
                #pragma unroll
                for (int e = 0; e < 8; ++e) h8[e] = pf[8 * u + e];
                *(half8*)&P16[sq * 64 + ((2 * w + u) ^ (sq & 7)) * 8] = h8;
            }
        }
        __syncthreads();

        // ---- carry update (Mq read next chunk, Tq read in epilogue) ----
        if (tid < 64) {
            const float mm = fmaxf(fmaxf(CM[tid * 4 + 0], CM[tid * 4 + 1]),
                                   fmaxf(CM[tid * 4 + 2], CM[tid * 4 + 3]));
            Mq[tid] = fmaxf(Mq[tid], mm);
            Tq[tid] += TSs[tid * 4 + 0] + TSs[tid * 4 + 1] + TSs[tid * 4 + 2] + TSs[tid * 4 + 3];
        }

        // ---- PV: Oacc[ni] += P[16w..][t] * V[t][16ni..] ----
        {
            half8 pa[2];
            #pragma unroll
            for (int kc = 0; kc < 2; ++kc) {
                const int row = 16 * w + fr;
                pa[kc] = *(const half8*)&P16[row * 64 + ((fh + 4 * kc) ^ (row & 7)) * 8];
            }
            #pragma unroll
            for (int ni = 0; ni < 4; ++ni)
                #pragma unroll
                for (int kc = 0; kc < 2; ++kc) {
                    const int dr = 16 * ni + fr;
                    half8 bf = *(const half8*)&Vt[dr * 64 + ((fh + 4 * kc) ^ (dr & 7)) * 8];
                    Oacc[ni] = __builtin_amdgcn_mfma_f32_16x16x32_f16(pa[kc], bf, Oacc[ni], 0, 0, 0);
                }
        }
    }

    __syncthreads();  // Tq final visibility

    // ---- epilogue: O / Tq -> o [B,S,H,Dh] f16 ----
    #pragma unroll
    for (int ni = 0; ni < 4; ++ni)
        #pragma unroll
        for (int r = 0; r < 4; ++r) {
            const int q  = 16 * w + 4 * fh + r;
            const float inv = 1.0f / Tq[q];
            o[((size_t)(b * S_LEN + qbase + q) * NHEADS + head) * DHEAD + fr + 16 * ni] =
                (_Float16)(Oacc[ni][r] * inv);
        }
}

extern "C" void kernel_launch(void* const* d_in, const int* in_sizes, int n_in,
                              void* d_out, int out_size, void* d_ws, size_t ws_size,
                              hipStream_t stream) {
    const float* x  = (const float*)d_in[0];
    const float* wq = (const float*)d_in[1];
    const float* bq = (const float*)d_in[2];
    const float* wk = (const float*)d_in[3];
    const float* bk = (const float*)d_in[4];
    const float* wv = (const float*)d_in[5];
    const float* bv = (const float*)d_in[6];
    const float* wo = (const float*)d_in[7];
    const float* bo = (const float*)d_in[8];

    const size_t BUF = (size_t)BATCH * S_LEN * DMODEL;   // 16,777,216 elems
    _Float16* xh  = (_Float16*)d_ws;
    _Float16* qh  = xh + BUF;
    _Float16* kh  = qh + BUF;       // qh/kh/vth must be consecutive (gemm z-offset)
    _Float16* vth = kh + BUF;
    _Float16* oh  = vth + BUF;
    _Float16* wqh = oh + BUF;
    _Float16* wkh = wqh + DMODEL * DMODEL;
    _Float16* wvh = wkh + DMODEL * DMODEL;
    _Float16* woh = wvh + DMODEL * DMODEL;               // total ~176 MB

    // 1) fp32 -> f16 conversions
    cvt_f32_f16<<<2048, 256, 0, stream>>>((const float4*)x,  (half4_t*)xh,  (int)(BUF / 4));
    cvt_f32_f16<<<512,  256, 0, stream>>>((const float4*)wq, (half4_t*)wqh, DMODEL * DMODEL / 4);
    cvt_f32_f16<<<512,  256, 0, stream>>>((const float4*)wk, (half4_t*)wkh, DMODEL * DMODEL / 4);
    cvt_f32_f16<<<512,  256, 0, stream>>>((const float4*)wv, (half4_t*)wvh, DMODEL * DMODEL / 4);
    cvt_f32_f16<<<512,  256, 0, stream>>>((const float4*)wo, (half4_t*)woh, DMODEL * DMODEL / 4);

    // 2) Q/K/V projections -> f16 q,k [B,H,S,Dh]; v^T [B,H,Dh,S]
    dim3 gproj(DMODEL / 128, (BATCH * S_LEN) / 128, 3);
    gemm_f16<0><<<gproj, 256, 0, stream>>>(xh, wqh, wkh, wvh, bq, bk, bv, (void*)qh);

    // 3) MFMA windowed attention -> oh f16 [B,S,H,Dh]
    dim3 gattn(S_LEN / 64, NHEADS, BATCH);
    attn_mfma<<<gattn, 256, 0, stream>>>(qh, kh, vth, oh);

    // 4) output projection -> fp32 d_out
    dim3 gout(DMODEL / 128, (BATCH * S_LEN) / 128, 1);
    gemm_f16<1><<<gout, 256, 0, stream>>>(oh, woh, nullptr, nullptr, bo, nullptr, nullptr,
                                          d_out);
}

// Round 5
// 297.591 us; speedup vs baseline: 20.5122x; 1.0996x over previous
//
#include <hip/hip_runtime.h>
#include <math.h>

#define S_LEN  4096
#define BATCH  4
#define DMODEL 1024
#define NHEADS 16
#define DHEAD  64
#define WIN    128

typedef _Float16 half8   __attribute__((ext_vector_type(8)));
typedef _Float16 half4_t __attribute__((ext_vector_type(4)));
typedef float    floatx4 __attribute__((ext_vector_type(4)));

__device__ __forceinline__ void gload16(const void* g, void* l) {
    __builtin_amdgcn_global_load_lds(
        (const __attribute__((address_space(1))) void*)g,
        (__attribute__((address_space(3))) void*)l, 16, 0, 0);
}

// ---------------- fp32 -> fp16 conversion (memory-bound) ----------------
__global__ __launch_bounds__(256)
void cvt_f32_f16(const float4* __restrict__ in, half4_t* __restrict__ out, int n4) {
    for (int i = blockIdx.x * blockDim.x + threadIdx.x; i < n4;
         i += gridDim.x * blockDim.x) {
        const float4 a = in[i];
        half4_t h;
        h[0] = (_Float16)a.x; h[1] = (_Float16)a.y;
        h[2] = (_Float16)a.z; h[3] = (_Float16)a.w;
        out[i] = h;
    }
}

// 4 weight matrices in one launch (blockIdx.y selects)
__global__ __launch_bounds__(256)
void cvt4_f32_f16(const float4* __restrict__ w0, const float4* __restrict__ w1,
                  const float4* __restrict__ w2, const float4* __restrict__ w3,
                  half4_t* __restrict__ o0, half4_t* __restrict__ o1,
                  half4_t* __restrict__ o2, half4_t* __restrict__ o3, int n4) {
    const float4* in  = blockIdx.y == 0 ? w0 : (blockIdx.y == 1 ? w1 : (blockIdx.y == 2 ? w2 : w3));
    half4_t*      out = blockIdx.y == 0 ? o0 : (blockIdx.y == 1 ? o1 : (blockIdx.y == 2 ? o2 : o3));
    for (int i = blockIdx.x * blockDim.x + threadIdx.x; i < n4;
         i += gridDim.x * blockDim.x) {
        const float4 a = in[i];
        half4_t h;
        h[0] = (_Float16)a.x; h[1] = (_Float16)a.y;
        h[2] = (_Float16)a.z; h[3] = (_Float16)a.w;
        out[i] = h;
    }
}

// ---------------- f16 MFMA GEMM (m97 structure, 128^2 tile, BK=32) -------
// A: [16384, 1024] f16.  W: [NT*128, 1024] f16 (row-major, dot along K).
// 1D grid of 128*NT blocks; bijective XCD swizzle: each XCD owns a 16-m-tile
// strip across all n (A-strip ~4MB L2-resident, W streamed).
// MODE 0 (NT=24): fused QKV. n0>>10 selects slab: z=0,1 -> f16 [B,H,S,Dh];
//                 z=2 -> f16 V^T [B,H,Dh,S]. bias from B0/B1/B2 by z.
// MODE 1 (NT=8):  fp32 flat [M,1024], bias B0.
template<int MODE, int NT>
__global__ __launch_bounds__(256)
void gemm128(const _Float16* __restrict__ A, const _Float16* __restrict__ W,
             const float* __restrict__ B0, const float* __restrict__ B1,
             const float* __restrict__ B2, void* __restrict__ out_base)
{
    const int K = DMODEL;

    // XCD swizzle: nwg = 128*NT, nwg%8==0 -> cpx = 16*NT
    const int bid = blockIdx.x;
    const int swz = (bid & 7) * (16 * NT) + (bid >> 3);
    const int i0  = (swz / NT) * 128;
    const int n0  = (swz % NT) * 128;

    __shared__ _Float16 As[128 * 32];
    __shared__ _Float16 Bs[128 * 32];

    const int tid  = threadIdx.x;
    const int lane = tid & 63;
    const int wid  = tid >> 6;
    const int wr   = wid >> 1, wc = wid & 1;

    const int srow = tid >> 2;
    const int scol = (tid & 3) * 8;
    const _Float16* gA0 = A + (size_t)(i0 + srow) * K + scol;
    const _Float16* gA1 = A + (size_t)(i0 + 64 + srow) * K + scol;
    const _Float16* gB0 = W + (size_t)(n0 + srow) * K + scol;
    const _Float16* gB1 = W + (size_t)(n0 + 64 + srow) * K + scol;
    _Float16* lA0 = As + tid * 8;
    _Float16* lA1 = As + 2048 + tid * 8;
    _Float16* lB0 = Bs + tid * 8;
    _Float16* lB1 = Bs + 2048 + tid * 8;

    floatx4 acc[4][4];
    #pragma unroll
    for (int mi = 0; mi < 4; ++mi)
        #pragma unroll
        for (int ni = 0; ni < 4; ++ni) acc[mi][ni] = (floatx4)0.f;

    const int frow = lane & 15;
    const int fk   = (lane >> 4) * 8;
    const int aoff = (wr * 64 + frow) * 32 + fk;
    const int boff = (wc * 64 + frow) * 32 + fk;

    for (int k0 = 0; k0 < K; k0 += 32) {
        gload16(gA0 + k0, lA0);
        gload16(gA1 + k0, lA1);
        gload16(gB0 + k0, lB0);
        gload16(gB1 + k0, lB1);
        __syncthreads();

        half8 a[4], b[4];
        #pragma unroll
        for (int mi = 0; mi < 4; ++mi) a[mi] = *(const half8*)&As[aoff + mi * 512];
        #pragma unroll
        for (int ni = 0; ni < 4; ++ni) b[ni] = *(const half8*)&Bs[boff + ni * 512];
        #pragma unroll
        for (int mi = 0; mi < 4; ++mi)
            #pragma unroll
            for (int ni = 0; ni < 4; ++ni)
                acc[mi][ni] = __builtin_amdgcn_mfma_f32_16x16x32_f16(
                    a[mi], b[ni], acc[mi][ni], 0, 0, 0);
        __syncthreads();
    }

    // epilogue: C/D layout col=lane&15, row=(lane>>4)*4+reg
    const int r0 = (lane >> 4) * 4;
    const int cn = lane & 15;
    const int z  = n0 >> 10;   // which of q/k/v (MODE 0); 0 for MODE 1
    const float* bz = (MODE == 1) ? B0 : (z == 0 ? B0 : (z == 1 ? B1 : B2));

    #pragma unroll
    for (int ni = 0; ni < 4; ++ni) {
        const int gc   = n0 + wc * 64 + ni * 16 + cn;
        const int gcol = gc & (DMODEL - 1);
        const float bv = bz[gcol];
        #pragma unroll
        for (int mi = 0; mi < 4; ++mi) {
            const int gr = i0 + wr * 64 + mi * 16 + r0;
            const floatx4 v = acc[mi][ni];
            if (MODE == 0) {
                _Float16* outh = (_Float16*)out_base
                               + (size_t)z * ((size_t)16384 * DMODEL);
                const int b  = gr >> 12;
                const int sp = gr & (S_LEN - 1);
                const int h  = gcol >> 6;
                const int dh = gcol & 63;
                if (z < 2) {
                    #pragma unroll
                    for (int r = 0; r < 4; ++r)
                        outh[((((size_t)(b * NHEADS + h)) * S_LEN + sp + r) << 6) + dh] =
                            (_Float16)(v[r] + bv);
                } else {
                    half4_t hv;
                    hv[0] = (_Float16)(v[0] + bv); hv[1] = (_Float16)(v[1] + bv);
                    hv[2] = (_Float16)(v[2] + bv); hv[3] = (_Float16)(v[3] + bv);
                    *(half4_t*)&outh[(((size_t)(b * NHEADS + h)) * DHEAD + dh) * S_LEN + sp] = hv;
                }
            } else {
                float* out = (float*)out_base;
                #pragma unroll
                for (int r = 0; r < 4; ++r)
                    out[(size_t)(gr + r) * DMODEL + gcol] = v[r] + bv;
            }
        }
    }
}

// ---------------- MFMA windowed attention, exact prefix-max scan ----------
// qh,kh: [B,H,S,Dh] f16; vth: [B,H,Dh,S] f16; o: [B,S,H,Dh] f16.
__global__ __launch_bounds__(256)
void attn_mfma(const _Float16* __restrict__ qh_, const _Float16* __restrict__ kh_,
               const _Float16* __restrict__ vth_, _Float16* __restrict__ o)
{
    __shared__ __align__(16) _Float16 Qs[64 * 64];
    __shared__ __align__(16) _Float16 Ks[64 * 64];
    __shared__ __align__(16) _Float16 Vt[64 * 64];
    __shared__ __align__(16) float    SP[64 * 68];
    __shared__ __align__(16) _Float16 P16[64 * 64];
    __shared__ float CM[64 * 4];
    __shared__ float TSs[64 * 4];
    __shared__ float Mq[64];
    __shared__ float Tq[64];

    const int tid   = threadIdx.x;
    const int lane  = tid & 63;
    const int w     = tid >> 6;
    const int qbase = blockIdx.x * 64;
    const int head  = blockIdx.y, b = blockIdx.z;
    const size_t bh = (size_t)(b * NHEADS + head);

    const _Float16* qg = qh_  + bh * (size_t)(S_LEN * DHEAD);
    const _Float16* kg = kh_  + bh * (size_t)(S_LEN * DHEAD);
    const _Float16* vg = vth_ + bh * (size_t)(DHEAD * S_LEN);

    const int fr = lane & 15;
    const int fh = lane >> 4;

    #pragma unroll
    for (int rep = 0; rep < 2; ++rep) {
        const int c = tid + 256 * rep;
        const int row = c >> 3, sl = c & 7;
        gload16(qg + (size_t)(qbase + row) * 64 + (size_t)((sl ^ (row & 7)) * 8),
                Qs + (size_t)c * 8);
    }
    if (tid < 64) { Mq[tid] = -INFINITY; Tq[tid] = 0.f; }

    floatx4 Oacc[4];
    #pragma unroll
    for (int ni = 0; ni < 4; ++ni) Oacc[ni] = (floatx4)0.f;

    for (int c = 0; c < 5; ++c) {
        const int jlo = qbase - WIN + c * 64;
        if (jlo < 0 || jlo >= S_LEN) continue;
        const int base_rel = jlo - qbase + WIN;

        __syncthreads();

        #pragma unroll
        for (int rep = 0; rep < 2; ++rep) {
            const int cc = tid + 256 * rep;
            const int row = cc >> 3, sl = cc & 7;
            gload16(kg + (size_t)(jlo + row) * 64 + (size_t)((sl ^ (row & 7)) * 8),
                    Ks + (size_t)cc * 8);
            gload16(vg + (size_t)row * S_LEN + jlo + (size_t)((sl ^ (row & 7)) * 8),
                    Vt + (size_t)cc * 8);
        }
        __syncthreads();

        {
            floatx4 acc[4];
            #pragma unroll
            for (int ni = 0; ni < 4; ++ni) acc[ni] = (floatx4)0.f;
            half8 a[2];
            #pragma unroll
            for (int kc = 0; kc < 2; ++kc) {
                const int row = 16 * w + fr;
                a[kc] = *(const half8*)&Qs[row * 64 + ((fh + 4 * kc) ^ (row & 7)) * 8];
            }
            #pragma unroll
            for (int ni = 0; ni < 4; ++ni)
                #pragma unroll
                for (int kc = 0; kc < 2; ++kc) {
                    const int tr = 16 * ni + fr;
                    half8 bf = *(const half8*)&Ks[tr * 64 + ((fh + 4 * kc) ^ (tr & 7)) * 8];
                    acc[ni] = __builtin_amdgcn_mfma_f32_16x16x32_f16(a[kc], bf, acc[ni], 0, 0, 0);
                }
            #pragma unroll
            for (int ni = 0; ni < 4; ++ni)
                #pragma unroll
                for (int r = 0; r < 4; ++r)
                    SP[(16 * w + 4 * fh + r) * 68 + fr + 16 * ni] = acc[ni][r] * 0.125f;
        }
        __syncthreads();

        const int sq = lane;
        float sv[16], run[16];
        {
            float m_run = -INFINITY;
            #pragma unroll
            for (int u = 0; u < 4; ++u) {
                const float4 s4 = *(const float4*)&SP[sq * 68 + w * 16 + 4 * u];
                const float se[4] = {s4.x, s4.y, s4.z, s4.w};
                #pragma unroll
                for (int e = 0; e < 4; ++e) {
                    const int i = 4 * u + e;
                    const int rel = base_rel + 16 * w + i - sq;
                    const bool valid = (rel >= 0) && (rel <= 2 * WIN);
                    const float s = valid ? se[e] : -INFINITY;
                    sv[i] = s;
                    m_run = fmaxf(m_run, s);
                    run[i] = m_run;
                }
            }
            CM[sq * 4 + w] = m_run;
        }
        __syncthreads();

        {
            float pre = Mq[sq];
            if (w > 0) pre = fmaxf(pre, CM[sq * 4 + 0]);
            if (w > 1) pre = fmaxf(pre, CM[sq * 4 + 1]);
            if (w > 2) pre = fmaxf(pre, CM[sq * 4 + 2]);
            float tl = 0.f;
            _Float16 pf[16];
            #pragma unroll
            for (int i = 0; i < 16; ++i) {
                const float wv = fmaxf(pre, run[i]);
                const float p = (sv[i] != -INFINITY) ? __expf(sv[i] - wv) : 0.f;
                tl += p;
                pf[i] = (_Float16)p;
            }
            TSs[sq * 4 + w] = tl;
            #pragma unroll
            for (int u = 0; u < 2; ++u) {
                half8 h8;
                #pragma unroll
                for (int e = 0; e < 8; ++e) h8[e] = pf[8 * u + e];
                *(half8*)&P16[sq * 64 + ((2 * w + u) ^ (sq & 7)) * 8] = h8;
            }
        }
        __syncthreads();

        if (tid < 64) {
            const float mm = fmaxf(fmaxf(CM[tid * 4 + 0], CM[tid * 4 + 1]),
                                   fmaxf(CM[tid * 4 + 2], CM[tid * 4 + 3]));
            Mq[tid] = fmaxf(Mq[tid], mm);
            Tq[tid] += TSs[tid * 4 + 0] + TSs[tid * 4 + 1] + TSs[tid * 4 + 2] + TSs[tid * 4 + 3];
        }

        {
            half8 pa[2];
            #pragma unroll
            for (int kc = 0; kc < 2; ++kc) {
                const int row = 16 * w + fr;
                pa[kc] = *(const half8*)&P16[row * 64 + ((fh + 4 * kc) ^ (row & 7)) * 8];
            }
            #pragma unroll
            for (int ni = 0; ni < 4; ++ni)
                #pragma unroll
                for (int kc = 0; kc < 2; ++kc) {
                    const int dr = 16 * ni + fr;
                    half8 bf = *(const half8*)&Vt[dr * 64 + ((fh + 4 * kc) ^ (dr & 7)) * 8];
                    Oacc[ni] = __builtin_amdgcn_mfma_f32_16x16x32_f16(pa[kc], bf, Oacc[ni], 0, 0, 0);
                }
        }
    }

    __syncthreads();

    #pragma unroll
    for (int ni = 0; ni < 4; ++ni)
        #pragma unroll
        for (int r = 0; r < 4; ++r) {
            const int q  = 16 * w + 4 * fh + r;
            const float inv = 1.0f / Tq[q];
            o[((size_t)(b * S_LEN + qbase + q) * NHEADS + head) * DHEAD + fr + 16 * ni] =
                (_Float16)(Oacc[ni][r] * inv);
        }
}

extern "C" void kernel_launch(void* const* d_in, const int* in_sizes, int n_in,
                              void* d_out, int out_size, void* d_ws, size_t ws_size,
                              hipStream_t stream) {
    const float* x  = (const float*)d_in[0];
    const float* wq = (const float*)d_in[1];
    const float* bq = (const float*)d_in[2];
    const float* wk = (const float*)d_in[3];
    const float* bk = (const float*)d_in[4];
    const float* wv = (const float*)d_in[5];
    const float* bv = (const float*)d_in[6];
    const float* wo = (const float*)d_in[7];
    const float* bo = (const float*)d_in[8];

    const size_t BUF = (size_t)BATCH * S_LEN * DMODEL;   // 16,777,216 elems
    _Float16* xh  = (_Float16*)d_ws;
    _Float16* qh  = xh + BUF;
    _Float16* kh  = qh + BUF;       // qh/kh/vth consecutive (z-slab offset)
    _Float16* vth = kh + BUF;
    _Float16* oh  = vth + BUF;
    _Float16* wqh = oh + BUF;       // wqh/wkh/wvh consecutive = W_all [3072,1024]
    _Float16* wkh = wqh + DMODEL * DMODEL;
    _Float16* wvh = wkh + DMODEL * DMODEL;
    _Float16* woh = wvh + DMODEL * DMODEL;

    // 1) fp32 -> f16 conversions (2 launches)
    cvt_f32_f16<<<2048, 256, 0, stream>>>((const float4*)x, (half4_t*)xh, (int)(BUF / 4));
    cvt4_f32_f16<<<dim3(256, 4), 256, 0, stream>>>(
        (const float4*)wq, (const float4*)wk, (const float4*)wv, (const float4*)wo,
        (half4_t*)wqh, (half4_t*)wkh, (half4_t*)wvh, (half4_t*)woh,
        DMODEL * DMODEL / 4);

    // 2) fused QKV projection: [16384,1024] @ [3072,1024]^T, XCD-swizzled
    gemm128<0, 24><<<128 * 24, 256, 0, stream>>>(xh, wqh, bq, bk, bv, (void*)qh);

    // 3) MFMA windowed attention -> oh f16 [B,S,H,Dh]
    dim3 gattn(S_LEN / 64, NHEADS, BATCH);
    attn_mfma<<<gattn, 256, 0, stream>>>(qh, kh, vth, oh);

    // 4) output projection -> fp32 d_out, XCD-swizzled
    gemm128<1, 8><<<128 * 8, 256, 0, stream>>>(oh, woh, bo, bo, bo, d_out);
}